// Round 1
// baseline (331.417 us; speedup 1.0000x reference)
//
#include <hip/hip_runtime.h>
#include <hip/hip_bf16.h>
#include <stdint.h>

// Problem constants
#define L_SEQ 2048
#define DI    2048
#define KTOT  8192          // D_CONV * DI
#define BM 128
#define BN 128
#define BK 64
#define NKT (KTOT / BK)     // 128
#define XPAD_ROWS 2052      // rows -1..2050 of x, zero-padded

typedef __attribute__((ext_vector_type(4))) float f32x4;
typedef __attribute__((ext_vector_type(8))) short bf16x8;

__device__ __forceinline__ unsigned short f2bf(float f) {
  union { float f; unsigned u; } v; v.f = f;
  unsigned r = v.u + 0x7FFFu + ((v.u >> 16) & 1u);   // RNE
  return (unsigned short)(r >> 16);
}

// xpad[r][i]: r==0 or r>=2049 -> 0, else bf16(x[r-1][i]). 4 elems/thread.
__global__ void prep_xpad(const float* __restrict__ x,
                          unsigned short* __restrict__ xpad) {
  const long e = ((long)blockIdx.x * blockDim.x + threadIdx.x) * 4;
  const int row = (int)(e >> 11);
  const int col = (int)(e & 2047);
  ushort4 o;
  if (row >= 1 && row <= L_SEQ) {
    const float4 v = *(const float4*)(x + (long)(row - 1) * DI + col);
    o.x = f2bf(v.x); o.y = f2bf(v.y); o.z = f2bf(v.z); o.w = f2bf(v.w);
  } else {
    o.x = 0; o.y = 0; o.z = 0; o.w = 0;
  }
  *(ushort4*)(xpad + e) = o;
}

// Bt[n][kk] = bf16(conv_kernel[kk][n]); conv_kernel is (KTOT, DI) row-major
// after flattening (w,i). LDS-tiled transpose, 32x32 tiles, block (32,8).
__global__ void prep_bt(const float* __restrict__ ck,
                        unsigned short* __restrict__ bt) {
  __shared__ float tile[32][33];
  const int kk0 = blockIdx.x * 32;
  const int n0  = blockIdx.y * 32;
  const int tx = threadIdx.x, ty = threadIdx.y;
#pragma unroll
  for (int j = 0; j < 4; ++j)
    tile[ty + j * 8][tx] = ck[(long)(kk0 + ty + j * 8) * DI + n0 + tx];
  __syncthreads();
#pragma unroll
  for (int j = 0; j < 4; ++j)
    bt[(long)(n0 + ty + j * 8) * KTOT + kk0 + tx] = f2bf(tile[tx][ty + j * 8]);
}

// C[t][o] = sum_kk A[t][kk] * B[kk][o],  A[t][kk] = xpad[t + (kk>>11)][kk&2047]
// 128x128 tile, BK=64, 4 waves in 2x2 (64x64 each), double-buffered LDS,
// global_load_lds width-16 staging, mfma_f32_16x16x32_bf16.
__global__ __launch_bounds__(256) void gemm_conv(
    const unsigned short* __restrict__ xpad,
    const unsigned short* __restrict__ bt,
    const float* __restrict__ bias,
    const float* __restrict__ dscale,
    float* __restrict__ out) {
  __shared__ unsigned short As[2][BM * BK];   // 16 KB each buf
  __shared__ unsigned short Bs[2][BN * BK];

  const int tid  = threadIdx.x;
  const int bm   = blockIdx.x >> 4;
  const int bn   = blockIdx.x & 15;
  const int lane = tid & 63;
  const int wid  = tid >> 6;
  const int wr   = wid >> 1;
  const int wc   = wid & 1;

  // staging decomposition: thread covers 8 contiguous bf16 per instr round
  const int sm0 = tid >> 3;          // 0..31 : row-in-tile base
  const int sk  = (tid & 7) * 8;     // 0..56 : k-in-tile

  f32x4 acc[4][4];
#pragma unroll
  for (int i = 0; i < 4; ++i)
#pragma unroll
    for (int j = 0; j < 4; ++j)
      acc[i][j] = (f32x4){0.f, 0.f, 0.f, 0.f};

  const int fm = lane & 15;          // fragment row/col within 16
  const int kq = (lane >> 4) * 8;    // fragment k base

  auto stage = [&](int buf, int kt) {
    const int w  = kt >> 5;                    // conv tap (BK=64 divides 2048)
    const int ca = (kt & 31) * BK + sk;        // column into x
    const unsigned short* gA = xpad + (long)(bm * BM + sm0 + w) * DI + ca;
    const unsigned short* gB = bt + (long)(bn * BN + sm0) * KTOT + kt * BK + sk;
    unsigned short* lA = &As[buf][tid * 8];
    unsigned short* lB = &Bs[buf][tid * 8];
#pragma unroll
    for (int r = 0; r < 4; ++r) {
      __builtin_amdgcn_global_load_lds(
          (const __attribute__((address_space(1))) void*)(gA + (long)r * 32 * DI),
          (__attribute__((address_space(3))) void*)(lA + r * 2048), 16, 0, 0);
      __builtin_amdgcn_global_load_lds(
          (const __attribute__((address_space(1))) void*)(gB + (long)r * 32 * KTOT),
          (__attribute__((address_space(3))) void*)(lB + r * 2048), 16, 0, 0);
    }
  };

  stage(0, 0);
  __syncthreads();

  int buf = 0;
  for (int kt = 0; kt < NKT; ++kt) {
    if (kt + 1 < NKT) stage(buf ^ 1, kt + 1);
#pragma unroll
    for (int s = 0; s < 2; ++s) {
      bf16x8 av[4], bv[4];
#pragma unroll
      for (int f = 0; f < 4; ++f)
        av[f] = *(const bf16x8*)&As[buf][(wr * 64 + f * 16 + fm) * BK + s * 32 + kq];
#pragma unroll
      for (int f = 0; f < 4; ++f)
        bv[f] = *(const bf16x8*)&Bs[buf][(wc * 64 + f * 16 + fm) * BK + s * 32 + kq];
#pragma unroll
      for (int i = 0; i < 4; ++i)
#pragma unroll
        for (int j = 0; j < 4; ++j)
          acc[i][j] = __builtin_amdgcn_mfma_f32_16x16x32_bf16(av[i], bv[j],
                                                              acc[i][j], 0, 0, 0);
    }
    __syncthreads();
    buf ^= 1;
  }

  // epilogue: out = (acc + conv_b[col]) * D_param[col]
  // C/D layout: col = lane&15, row = (lane>>4)*4 + q   [m89/m91 verified]
  const int r0 = bm * BM + wr * 64;
  const int c0 = bn * BN + wc * 64;
#pragma unroll
  for (int j = 0; j < 4; ++j) {
    const int col = c0 + j * 16 + fm;
    const float bb = bias[col];
    const float dd = dscale[col];
#pragma unroll
    for (int i = 0; i < 4; ++i) {
      const int row = r0 + i * 16 + (lane >> 4) * 4;
#pragma unroll
      for (int q = 0; q < 4; ++q)
        out[(long)(row + q) * DI + col] = (acc[i][j][q] + bb) * dd;
    }
  }
}

extern "C" void kernel_launch(void* const* d_in, const int* in_sizes, int n_in,
                              void* d_out, int out_size, void* d_ws, size_t ws_size,
                              hipStream_t stream) {
  // inputs: 0=x, 1=dt_W (dead), 2=dt_b (dead), 3=conv_kernel, 4=conv_b,
  //         5=A_param (dead: scan ys are xt), 6=D_param
  const float* x  = (const float*)d_in[0];
  const float* ck = (const float*)d_in[3];
  const float* cb = (const float*)d_in[4];
  const float* Dp = (const float*)d_in[6];
  float* out = (float*)d_out;

  // ws layout: xpad bf16 (2052*2048 = 8.4 MB), Bt bf16 (2048*8192 = 33.6 MB)
  unsigned short* xpad = (unsigned short*)d_ws;
  unsigned short* Bt =
      (unsigned short*)((char*)d_ws + (size_t)XPAD_ROWS * DI * sizeof(unsigned short));

  prep_xpad<<<(XPAD_ROWS * DI) / (4 * 256), 256, 0, stream>>>(x, xpad);
  prep_bt<<<dim3(KTOT / 32, DI / 32), dim3(32, 8), 0, stream>>>(ck, Bt);
  gemm_conv<<<(L_SEQ / BM) * (DI / BN), 256, 0, stream>>>(xpad, Bt, cb, Dp, out);
}

// Round 2
// 312.768 us; speedup vs baseline: 1.0596x; 1.0596x over previous
//
#include <hip/hip_runtime.h>
#include <hip/hip_bf16.h>
#include <stdint.h>

// Problem constants
#define L_SEQ 2048
#define DI    2048
#define KTOT  8192          // D_CONV * DI
#define BM 128
#define BN 64
#define BK 64
#define NKT (KTOT / BK)     // 128
#define XPAD_ROWS 2052      // rows -1..2050 of x, zero-padded

typedef __attribute__((ext_vector_type(4))) float f32x4;
typedef __attribute__((ext_vector_type(8))) short bf16x8;

__device__ __forceinline__ unsigned short f2bf(float f) {
  union { float f; unsigned u; } v; v.f = f;
  unsigned r = v.u + 0x7FFFu + ((v.u >> 16) & 1u);   // RNE
  return (unsigned short)(r >> 16);
}

// xpad[r][i]: r==0 or r>=2049 -> 0, else bf16(x[r-1][i]). 4 elems/thread.
__global__ void prep_xpad(const float* __restrict__ x,
                          unsigned short* __restrict__ xpad) {
  const long e = ((long)blockIdx.x * blockDim.x + threadIdx.x) * 4;
  const int row = (int)(e >> 11);
  const int col = (int)(e & 2047);
  ushort4 o;
  if (row >= 1 && row <= L_SEQ) {
    const float4 v = *(const float4*)(x + (long)(row - 1) * DI + col);
    o.x = f2bf(v.x); o.y = f2bf(v.y); o.z = f2bf(v.z); o.w = f2bf(v.w);
  } else {
    o.x = 0; o.y = 0; o.z = 0; o.w = 0;
  }
  *(ushort4*)(xpad + e) = o;
}

// Bt[n][w*2048+i] = bf16(ck[w][i][n]). 64x64 tile per block, one w-slice.
// Load: coalesced float4 rows -> padded LDS. Store: 16B (8 bf16) per thread.
__global__ __launch_bounds__(256) void prep_bt(const float* __restrict__ ck,
                                               unsigned short* __restrict__ bt) {
  __shared__ float tile[64][65];
  const int w  = blockIdx.z;
  const int i0 = blockIdx.x * 64;
  const int n0 = blockIdx.y * 64;
  const int t  = threadIdx.x;
  const float* src = ck + ((long)w * 2048 + i0) * DI + n0;
#pragma unroll
  for (int r = 0; r < 4; ++r) {
    const int row = r * 16 + (t >> 4);
    const int c4  = (t & 15) * 4;
    const float4 v = *(const float4*)(src + (long)row * DI + c4);
    tile[row][c4 + 0] = v.x;
    tile[row][c4 + 1] = v.y;
    tile[row][c4 + 2] = v.z;
    tile[row][c4 + 3] = v.w;
  }
  __syncthreads();
#pragma unroll
  for (int j2 = 0; j2 < 2; ++j2) {
    const int n  = (t >> 3) + j2 * 32;
    const int ic = (t & 7) * 8;
    union { unsigned short u[8]; uint4 v; } o;
#pragma unroll
    for (int j = 0; j < 8; ++j) o.u[j] = f2bf(tile[ic + j][n]);
    *(uint4*)(bt + (long)(n0 + n) * KTOT + (long)w * 2048 + i0 + ic) = o.v;
  }
}

// C[t][o] = sum_kk A[t][kk] * B[kk][o],  A[t][kk] = xpad[t + (kk>>11)][kk&2047]
// 128x64 tile, BK=64, 4 waves in 2x2 (64x32 each), double-buffered LDS,
// global_load_lds width-16 staging, mfma_f32_16x16x32_bf16.
// Grid 512 blocks -> 2 blocks/CU: inter-block overlap hides barrier drain.
__global__ __launch_bounds__(256) void gemm_conv(
    const unsigned short* __restrict__ xpad,
    const unsigned short* __restrict__ bt,
    const float* __restrict__ bias,
    const float* __restrict__ dscale,
    float* __restrict__ out) {
  __shared__ unsigned short As[2][BM * BK];   // 16 KB per buf
  __shared__ unsigned short Bs[2][BN * BK];   // 8 KB per buf

  const int tid  = threadIdx.x;
  const int bm   = blockIdx.x >> 5;           // 16 M-tiles
  const int bn   = blockIdx.x & 31;           // 32 N-tiles
  const int lane = tid & 63;
  const int wid  = tid >> 6;
  const int wr   = wid >> 1;                  // wave M: 0..1 (64 rows)
  const int wc   = wid & 1;                   // wave N: 0..1 (32 cols)

  const int sm0 = tid >> 3;                   // 0..31 staging row base
  const int sk  = (tid & 7) * 8;              // k-in-tile (8 bf16 = 16B)

  f32x4 acc[4][2];
#pragma unroll
  for (int i = 0; i < 4; ++i)
#pragma unroll
    for (int j = 0; j < 2; ++j)
      acc[i][j] = (f32x4){0.f, 0.f, 0.f, 0.f};

  const int fm = lane & 15;
  const int kq = (lane >> 4) * 8;

  auto stage = [&](int buf, int kt) {
    const int w  = kt >> 5;                   // conv tap (BK=64 divides 2048)
    const int ca = (kt & 31) * BK + sk;       // column into x
    const unsigned short* gA = xpad + (long)(bm * BM + sm0 + w) * DI + ca;
    const unsigned short* gB = bt + (long)(bn * BN + sm0) * KTOT + kt * BK + sk;
    unsigned short* lA = &As[buf][tid * 8];
    unsigned short* lB = &Bs[buf][tid * 8];
#pragma unroll
    for (int r = 0; r < 4; ++r)
      __builtin_amdgcn_global_load_lds(
          (const __attribute__((address_space(1))) void*)(gA + (long)r * 32 * DI),
          (__attribute__((address_space(3))) void*)(lA + r * 2048), 16, 0, 0);
#pragma unroll
    for (int r = 0; r < 2; ++r)
      __builtin_amdgcn_global_load_lds(
          (const __attribute__((address_space(1))) void*)(gB + (long)r * 32 * KTOT),
          (__attribute__((address_space(3))) void*)(lB + r * 2048), 16, 0, 0);
  };

  stage(0, 0);
  __syncthreads();

  int buf = 0;
  for (int kt = 0; kt < NKT; ++kt) {
    if (kt + 1 < NKT) stage(buf ^ 1, kt + 1);
#pragma unroll
    for (int s = 0; s < 2; ++s) {
      bf16x8 av[4], bv[2];
#pragma unroll
      for (int f = 0; f < 4; ++f)
        av[f] = *(const bf16x8*)&As[buf][(wr * 64 + f * 16 + fm) * BK + s * 32 + kq];
#pragma unroll
      for (int f = 0; f < 2; ++f)
        bv[f] = *(const bf16x8*)&Bs[buf][(wc * 32 + f * 16 + fm) * BK + s * 32 + kq];
#pragma unroll
      for (int i = 0; i < 4; ++i)
#pragma unroll
        for (int j = 0; j < 2; ++j)
          acc[i][j] = __builtin_amdgcn_mfma_f32_16x16x32_bf16(av[i], bv[j],
                                                              acc[i][j], 0, 0, 0);
    }
    __syncthreads();
    buf ^= 1;
  }

  // epilogue: out = (acc + conv_b[col]) * D_param[col]
  // C/D layout: col = lane&15, row = (lane>>4)*4 + q   [m89/m91 verified]
  const int r0 = bm * BM + wr * 64;
  const int c0 = bn * BN + wc * 32;
#pragma unroll
  for (int j = 0; j < 2; ++j) {
    const int col = c0 + j * 16 + fm;
    const float bb = bias[col];
    const float dd = dscale[col];
#pragma unroll
    for (int i = 0; i < 4; ++i) {
      const int row = r0 + i * 16 + (lane >> 4) * 4;
#pragma unroll
      for (int q = 0; q < 4; ++q)
        out[(long)(row + q) * DI + col] = (acc[i][j][q] + bb) * dd;
    }
  }
}

extern "C" void kernel_launch(void* const* d_in, const int* in_sizes, int n_in,
                              void* d_out, int out_size, void* d_ws, size_t ws_size,
                              hipStream_t stream) {
  // inputs: 0=x, 1=dt_W (dead), 2=dt_b (dead), 3=conv_kernel, 4=conv_b,
  //         5=A_param (dead: scan ys are xt), 6=D_param
  const float* x  = (const float*)d_in[0];
  const float* ck = (const float*)d_in[3];
  const float* cb = (const float*)d_in[4];
  const float* Dp = (const float*)d_in[6];
  float* out = (float*)d_out;

  // ws layout: xpad bf16 (2052*2048 = 8.4 MB), Bt bf16 (2048*8192 = 33.6 MB)
  unsigned short* xpad = (unsigned short*)d_ws;
  unsigned short* Bt =
      (unsigned short*)((char*)d_ws + (size_t)XPAD_ROWS * DI * sizeof(unsigned short));

  prep_xpad<<<(XPAD_ROWS * DI) / (4 * 256), 256, 0, stream>>>(x, xpad);
  prep_bt<<<dim3(32, 32, 4), 256, 0, stream>>>(ck, Bt);
  gemm_conv<<<(L_SEQ / BM) * (DI / BN), 256, 0, stream>>>(xpad, Bt, cb, Dp, out);
}

// Round 3
// 248.452 us; speedup vs baseline: 1.3339x; 1.2589x over previous
//
#include <hip/hip_runtime.h>
#include <hip/hip_bf16.h>
#include <stdint.h>

// Problem constants
#define L_SEQ 2048
#define DI    2048
#define KTOT  8192          // D_CONV * DI
#define BM 128
#define BN 128
#define BK 64
#define KSTEPS (2048 / BK)  // 32 K-steps per tap
#define XPAD_ROWS 2052      // rows -1..2050 of x, zero-padded

typedef __attribute__((ext_vector_type(4))) float f32x4;
typedef __attribute__((ext_vector_type(8))) short bf16x8;

__device__ __forceinline__ unsigned short f2bf(float f) {
  union { float f; unsigned u; } v; v.f = f;
  unsigned r = v.u + 0x7FFFu + ((v.u >> 16) & 1u);   // RNE
  return (unsigned short)(r >> 16);
}

// xpad[r][i]: r==0 or r>=2049 -> 0, else bf16(x[r-1][i]). 4 elems/thread.
__global__ void prep_xpad(const float* __restrict__ x,
                          unsigned short* __restrict__ xpad) {
  const long e = ((long)blockIdx.x * blockDim.x + threadIdx.x) * 4;
  const int row = (int)(e >> 11);
  const int col = (int)(e & 2047);
  ushort4 o;
  if (row >= 1 && row <= L_SEQ) {
    const float4 v = *(const float4*)(x + (long)(row - 1) * DI + col);
    o.x = f2bf(v.x); o.y = f2bf(v.y); o.z = f2bf(v.z); o.w = f2bf(v.w);
  } else {
    o.x = 0; o.y = 0; o.z = 0; o.w = 0;
  }
  *(ushort4*)(xpad + e) = o;
}

// Bt[n][w*2048+i] = bf16(ck[w][i][n]). 64x64 tile per block, one w-slice.
__global__ __launch_bounds__(256) void prep_bt(const float* __restrict__ ck,
                                               unsigned short* __restrict__ bt) {
  __shared__ float tile[64][65];
  const int w  = blockIdx.z;
  const int i0 = blockIdx.x * 64;
  const int n0 = blockIdx.y * 64;
  const int t  = threadIdx.x;
  const float* src = ck + ((long)w * 2048 + i0) * DI + n0;
#pragma unroll
  for (int r = 0; r < 4; ++r) {
    const int row = r * 16 + (t >> 4);
    const int c4  = (t & 15) * 4;
    const float4 v = *(const float4*)(src + (long)row * DI + c4);
    tile[row][c4 + 0] = v.x;
    tile[row][c4 + 1] = v.y;
    tile[row][c4 + 2] = v.z;
    tile[row][c4 + 3] = v.w;
  }
  __syncthreads();
#pragma unroll
  for (int j2 = 0; j2 < 2; ++j2) {
    const int n  = (t >> 3) + j2 * 32;
    const int ic = (t & 7) * 8;
    union { unsigned short u[8]; uint4 v; } o;
#pragma unroll
    for (int j = 0; j < 8; ++j) o.u[j] = f2bf(tile[ic + j][n]);
    *(uint4*)(bt + (long)(n0 + n) * KTOT + (long)w * 2048 + i0 + ic) = o.v;
  }
}

// Split-K by conv tap: block (bm, bn, w) computes the 128x128 tile's partial
// sum over i in [0,2048) for tap w:  sum_i xpad[t+w][i] * Bt[o][w*2048+i],
// atomically accumulated into out (zero-initialized). Bias seeded at w==0,
// D_param folded into the epilogue multiply.
// m97 structure: 128x128 tile, BK=64, single-buffered 32KB LDS, 4 waves
// (2x2 of 64x64), 32 MFMA/step/wave, grid 1024 -> 4 resident blocks/CU.
__global__ __launch_bounds__(256, 4) void gemm_conv(
    const unsigned short* __restrict__ xpad,
    const unsigned short* __restrict__ bt,
    const float* __restrict__ bias,
    const float* __restrict__ dscale,
    float* __restrict__ out) {
  __shared__ unsigned short As[BM * BK];   // 16 KB
  __shared__ unsigned short Bs[BN * BK];   // 16 KB

  const int tid  = threadIdx.x;
  const int bm   = blockIdx.x >> 4;           // 16 M-tiles
  const int bn   = blockIdx.x & 15;           // 16 N-tiles
  const int w    = blockIdx.y;                // conv tap 0..3
  const int lane = tid & 63;
  const int wid  = tid >> 6;
  const int wr   = wid >> 1;
  const int wc   = wid & 1;

  const int sm0 = tid >> 3;                   // staging row base 0..31
  const int sk  = (tid & 7) * 8;              // k offset (8 bf16 = 16B)

  f32x4 acc[4][4];
#pragma unroll
  for (int i = 0; i < 4; ++i)
#pragma unroll
    for (int j = 0; j < 4; ++j)
      acc[i][j] = (f32x4){0.f, 0.f, 0.f, 0.f};

  const int fm = lane & 15;
  const int kq = (lane >> 4) * 8;

  // A rows: t + w - 1 in x == row t + w of xpad
  const unsigned short* gA0 = xpad + (long)(bm * BM + sm0 + w) * DI + sk;
  const unsigned short* gB0 = bt + (long)(bn * BN + sm0) * KTOT + (long)w * 2048 + sk;
  unsigned short* lA = &As[tid * 8];
  unsigned short* lB = &Bs[tid * 8];

  for (int kt = 0; kt < KSTEPS; ++kt) {
    const unsigned short* gA = gA0 + kt * BK;
    const unsigned short* gB = gB0 + kt * BK;
#pragma unroll
    for (int r = 0; r < 4; ++r) {
      __builtin_amdgcn_global_load_lds(
          (const __attribute__((address_space(1))) void*)(gA + (long)r * 32 * DI),
          (__attribute__((address_space(3))) void*)(lA + r * 2048), 16, 0, 0);
      __builtin_amdgcn_global_load_lds(
          (const __attribute__((address_space(1))) void*)(gB + (long)r * 32 * KTOT),
          (__attribute__((address_space(3))) void*)(lB + r * 2048), 16, 0, 0);
    }
    __syncthreads();   // drains vmcnt(0): LDS ready
#pragma unroll
    for (int s = 0; s < 2; ++s) {
      bf16x8 av[4], bv[4];
#pragma unroll
      for (int f = 0; f < 4; ++f)
        av[f] = *(const bf16x8*)&As[(wr * 64 + f * 16 + fm) * BK + s * 32 + kq];
#pragma unroll
      for (int f = 0; f < 4; ++f)
        bv[f] = *(const bf16x8*)&Bs[(wc * 64 + f * 16 + fm) * BK + s * 32 + kq];
#pragma unroll
      for (int i = 0; i < 4; ++i)
#pragma unroll
        for (int j = 0; j < 4; ++j)
          acc[i][j] = __builtin_amdgcn_mfma_f32_16x16x32_bf16(av[i], bv[j],
                                                              acc[i][j], 0, 0, 0);
    }
    __syncthreads();   // protect LDS before next stage
  }

  // epilogue: atomic accumulate (acc [+ bias if w==0]) * D into out
  // C/D layout: col = lane&15, row = (lane>>4)*4 + q   [m89/m91 verified]
  const int r0 = bm * BM + wr * 64;
  const int c0 = bn * BN + wc * 64;
#pragma unroll
  for (int j = 0; j < 4; ++j) {
    const int col = c0 + j * 16 + fm;
    const float bb = (w == 0) ? bias[col] : 0.f;
    const float dd = dscale[col];
#pragma unroll
    for (int i = 0; i < 4; ++i) {
      const int row = r0 + i * 16 + (lane >> 4) * 4;
#pragma unroll
      for (int q = 0; q < 4; ++q)
        atomicAdd(&out[(long)(row + q) * DI + col], (acc[i][j][q] + bb) * dd);
    }
  }
}

extern "C" void kernel_launch(void* const* d_in, const int* in_sizes, int n_in,
                              void* d_out, int out_size, void* d_ws, size_t ws_size,
                              hipStream_t stream) {
  // inputs: 0=x, 1=dt_W (dead), 2=dt_b (dead), 3=conv_kernel, 4=conv_b,
  //         5=A_param (dead: scan ys are xt), 6=D_param
  const float* x  = (const float*)d_in[0];
  const float* ck = (const float*)d_in[3];
  const float* cb = (const float*)d_in[4];
  const float* Dp = (const float*)d_in[6];
  float* out = (float*)d_out;

  // ws layout: xpad bf16 (2052*2048 = 8.4 MB), Bt bf16 (2048*8192 = 33.6 MB)
  unsigned short* xpad = (unsigned short*)d_ws;
  unsigned short* Bt =
      (unsigned short*)((char*)d_ws + (size_t)XPAD_ROWS * DI * sizeof(unsigned short));

  prep_xpad<<<(XPAD_ROWS * DI) / (4 * 256), 256, 0, stream>>>(x, xpad);
  prep_bt<<<dim3(32, 32, 4), 256, 0, stream>>>(ck, Bt);
  hipMemsetAsync(d_out, 0, (size_t)out_size * sizeof(float), stream);
  gemm_conv<<<dim3(16 * 16, 4), 256, 0, stream>>>(xpad, Bt, cb, Dp, out);
}